// Round 1
// baseline (65.072 us; speedup 1.0000x reference)
//
#include <hip/hip_runtime.h>
#include <stdint.h>

// Problem constants
#define B_  32
#define S_  512
#define C_  320
#define H_  512

typedef __attribute__((ext_vector_type(8))) short short8;
typedef __attribute__((ext_vector_type(4))) float f32x4;

__device__ __forceinline__ unsigned short f2bf(float x){
  unsigned u = __builtin_bit_cast(unsigned, x);
  u = u + 0x7FFFu + ((u >> 16) & 1u);          // round-to-nearest-even
  return (unsigned short)(u >> 16);
}
__device__ __forceinline__ float bf2f(unsigned short h){
  unsigned u = ((unsigned)h) << 16;
  return __builtin_bit_cast(float, u);
}
__device__ __forceinline__ float sigf(float x){ return 1.0f/(1.0f + __expf(-x)); }
__device__ __forceinline__ float tanh_fast(float x){ return 2.0f/(1.0f + __expf(-2.0f*x)) - 1.0f; }

__device__ __forceinline__ void gload16(const void* g, void* l){
  __builtin_amdgcn_global_load_lds((const __attribute__((address_space(1))) void*)g,
                                   (__attribute__((address_space(3))) void*)l, 16, 0, 0);
}

// ---------------- Pass 0a: cast w_ih (2048x512 f32) -> bf16, same layout ----
__global__ __launch_bounds__(256) void k_cast_w(const float* __restrict__ w,
                                                unsigned short* __restrict__ wws){
  int idx = blockIdx.x*256 + threadIdx.x;      // float4 units; 2048*512/4 = 262144
  float4 v = ((const float4*)w)[idx];
  uint2 p;
  p.x = (unsigned)f2bf(v.x) | ((unsigned)f2bf(v.y) << 16);
  p.y = (unsigned)f2bf(v.z) | ((unsigned)f2bf(v.w) << 16);
  ((uint2*)wws)[idx] = p;
}

// ---------------- Pass 0b: x (b,s,c) f32 -> xws[b][c][s] bf16 (transpose) ---
__global__ __launch_bounds__(256) void k_cast_tx(const float* __restrict__ x,
                                                 unsigned short* __restrict__ xws){
  __shared__ float lds[64][65];
  const int tid = threadIdx.x;
  const int st = blockIdx.x, ctt = blockIdx.y, b = blockIdx.z;
  const int s0 = st*64, c0 = ctt*64;
  const int row = tid >> 2, q = tid & 3;

  const float* src = x + ((size_t)(b*S_ + s0 + row))*C_ + c0 + q*16;
  #pragma unroll
  for (int j = 0; j < 4; j++){
    float4 v = ((const float4*)src)[j];
    lds[row][q*16 + j*4 + 0] = v.x;
    lds[row][q*16 + j*4 + 1] = v.y;
    lds[row][q*16 + j*4 + 2] = v.z;
    lds[row][q*16 + j*4 + 3] = v.w;
  }
  __syncthreads();
  const int crow = row;
  #pragma unroll
  for (int j = 0; j < 2; j++){
    short8 o;
    #pragma unroll
    for (int e = 0; e < 8; e++)
      o[e] = (short)f2bf(lds[q*16 + j*8 + e][crow]);
    *(short8*)(xws + ((size_t)(b*C_ + c0 + crow))*S_ + s0 + q*16 + j*8) = o;
  }
}

// ---------------- Pass 1: MFMA GEMM + LSTM-cell epilogue --------------------
// gatesT[g, c] = sum_s wws[g,s] * xws[b,c,s]; only gate blocks {i=0, g=2, o=3}.
// Block: (kt, ct, b): 64 k-rows x 3 gates (M), 64 c (N), K = 512 in steps of 64.
// Wave w owns k-rows [w*16, w*16+16) of every gate -> gate combine in-register.
__global__ __launch_bounds__(256) void k_gemm(const unsigned short* __restrict__ wws,
                                              const unsigned short* __restrict__ xws,
                                              const float* __restrict__ b_ih,
                                              const float* __restrict__ b_hh,
                                              unsigned short* __restrict__ hws){
  __shared__ alignas(16) unsigned short ldsA[3*64*64];  // [gate][row 64][s 64], swizzled
  __shared__ alignas(16) unsigned short ldsB[64*64];    // [c-row 64][s 64], swizzled

  const int tid  = threadIdx.x;
  const int w    = tid >> 6;
  const int lane = tid & 63;
  const int kt = blockIdx.x, ct = blockIdx.y, b = blockIdx.z;
  const int k0 = kt*64, c0 = ct*64;

  f32x4 acc[3][4];
  #pragma unroll
  for (int gi = 0; gi < 3; gi++)
    #pragma unroll
    for (int nf = 0; nf < 4; nf++)
      acc[gi][nf] = (f32x4){0.f, 0.f, 0.f, 0.f};

  // staging geometry: each global_load_lds = 1024B = 8 rows of 128B.
  // LDS slot (row, colb) holds global element (row, colb ^ ((row&7)<<4)).
  const int cr   = lane >> 3;                    // row within an 8-row chunk
  const int slot = ((lane & 7) ^ cr) << 4;       // pre-swizzled source col byte

  for (int s0 = 0; s0 < S_; s0 += 64){
    #pragma unroll
    for (int i = 0; i < 8; i++){
      int q = w*8 + i;                           // 32 chunks: 24 A + 8 B
      if (q < 24){
        int gi = q >> 3, q8 = q & 7;
        int gr = (gi == 0 ? 0 : (gi == 1 ? 1024 : 1536));   // gate row-block base
        int grow = gr + k0 + q8*8 + cr;
        const char* src = (const char*)wws + ((size_t)grow*S_ + s0)*2 + slot;
        char* dst = (char*)ldsA + gi*8192 + q8*1024;
        gload16(src, dst);
      } else {
        int q8 = q - 24;
        int xrow = b*C_ + c0 + q8*8 + cr;
        const char* src = (const char*)xws + ((size_t)xrow*S_ + s0)*2 + slot;
        char* dst = (char*)ldsB + q8*1024;
        gload16(src, dst);
      }
    }
    __syncthreads();   // compiler drains vmcnt before s_barrier

    #pragma unroll
    for (int ks = 0; ks < 2; ks++){
      const int colb = (ks*64 + ((lane >> 4) << 4)) ^ ((lane & 7) << 4);
      const int arow = w*16 + (lane & 15);
      short8 aF[3], bF[4];
      #pragma unroll
      for (int gi = 0; gi < 3; gi++)
        aF[gi] = *(const short8*)((const char*)ldsA + gi*8192 + arow*128 + colb);
      #pragma unroll
      for (int nf = 0; nf < 4; nf++){
        int brow = nf*16 + (lane & 15);
        bF[nf] = *(const short8*)((const char*)ldsB + brow*128 + colb);
      }
      #pragma unroll
      for (int gi = 0; gi < 3; gi++)
        #pragma unroll
        for (int nf = 0; nf < 4; nf++)
          acc[gi][nf] = __builtin_amdgcn_mfma_f32_16x16x32_bf16(aF[gi], bF[nf], acc[gi][nf], 0, 0, 0);
    }
    __syncthreads();
  }

  // epilogue: gates -> h, write bf16 h_ws[n][k], n = c*32 + b
  const int lkb = k0 + w*16 + ((lane >> 4) << 2);   // global k for acc regs r=0..3
  float bi[4], bg[4], bo[4];
  #pragma unroll
  for (int r = 0; r < 4; r++){
    bi[r] = b_ih[lkb + r]        + b_hh[lkb + r];          // i-gate rows [0,512)
    bg[r] = b_ih[1024 + lkb + r] + b_hh[1024 + lkb + r];   // g-gate rows [1024,1536)
    bo[r] = b_ih[1536 + lkb + r] + b_hh[1536 + lkb + r];   // o-gate rows [1536,2048)
  }
  #pragma unroll
  for (int nf = 0; nf < 4; nf++){
    int c = c0 + nf*16 + (lane & 15);
    size_t n = (size_t)c*32 + (size_t)b;
    float h[4];
    #pragma unroll
    for (int r = 0; r < 4; r++){
      float iv = acc[0][nf][r] + bi[r];
      float gv = acc[1][nf][r] + bg[r];
      float ov = acc[2][nf][r] + bo[r];
      float cc = sigf(iv) * tanh_fast(gv);
      h[r] = sigf(ov) * tanh_fast(cc);
    }
    uint2 p;
    p.x = (unsigned)f2bf(h[0]) | ((unsigned)f2bf(h[1]) << 16);
    p.y = (unsigned)f2bf(h[2]) | ((unsigned)f2bf(h[3]) << 16);
    *(uint2*)(hws + n*H_ + lkb) = p;
  }
}

// ---------------- Pass 2: out[b2,k,c2] = h_ws[b2*320+c2][k] (f32 out) -------
__global__ __launch_bounds__(256) void k_out(const unsigned short* __restrict__ hws,
                                             float* __restrict__ out){
  __shared__ float lds[64][65];
  const int tid = threadIdx.x;
  const int kt = blockIdx.x, ctt = blockIdx.y, b2 = blockIdx.z;
  const int k0 = kt*64, n0 = b2*320 + ctt*64;
  const int rr = tid >> 2, q = tid & 3;

  #pragma unroll
  for (int j = 0; j < 2; j++){
    short8 v = *(const short8*)(hws + ((size_t)(n0 + rr))*H_ + k0 + q*16 + j*8);
    #pragma unroll
    for (int e = 0; e < 8; e++)
      lds[rr][q*16 + j*8 + e] = bf2f((unsigned short)v[e]);
  }
  __syncthreads();
  const int krow = rr;
  #pragma unroll
  for (int j = 0; j < 4; j++){
    int c2l = q*16 + j*4;
    float4 o;
    o.x = lds[c2l + 0][krow];
    o.y = lds[c2l + 1][krow];
    o.z = lds[c2l + 2][krow];
    o.w = lds[c2l + 3][krow];
    *(float4*)(out + (size_t)b2*(H_*C_) + (size_t)(k0 + krow)*C_ + ctt*64 + c2l) = o;
  }
}

extern "C" void kernel_launch(void* const* d_in, const int* in_sizes, int n_in,
                              void* d_out, int out_size, void* d_ws, size_t ws_size,
                              hipStream_t stream){
  const float* x    = (const float*)d_in[0];
  const float* w_ih = (const float*)d_in[1];
  // d_in[2] = w_hh is mathematically dead (h0 = 0)
  const float* b_ih = (const float*)d_in[3];
  const float* b_hh = (const float*)d_in[4];
  float* out = (float*)d_out;

  char* ws = (char*)d_ws;
  unsigned short* wws = (unsigned short*)(ws);                           // 2 MiB  (2048*512 bf16)
  unsigned short* xws = (unsigned short*)(ws + 2097152);                 // 10 MiB (32*320*512 bf16)
  unsigned short* hws = (unsigned short*)(ws + 2097152 + 10485760);      // 10 MiB (10240*512 bf16)
  // total workspace use: ~22 MiB

  k_cast_w <<<1024, 256, 0, stream>>>(w_ih, wws);
  k_cast_tx<<<dim3(8, 5, 32), 256, 0, stream>>>(x, xws);
  k_gemm   <<<dim3(8, 5, 32), 256, 0, stream>>>(wws, xws, b_ih, b_hh, hws);
  k_out    <<<dim3(8, 5, 32), 256, 0, stream>>>(hws, out);
}

// Round 2
// 59.034 us; speedup vs baseline: 1.1023x; 1.1023x over previous
//
#include <hip/hip_runtime.h>
#include <stdint.h>

// Problem constants
#define B_  32
#define S_  512
#define C_  320
#define H_  512

typedef __attribute__((ext_vector_type(8))) short short8;
typedef __attribute__((ext_vector_type(4))) float f32x4;

__device__ __forceinline__ unsigned short f2bf(float x){
  unsigned u = __builtin_bit_cast(unsigned, x);
  u = u + 0x7FFFu + ((u >> 16) & 1u);          // round-to-nearest-even
  return (unsigned short)(u >> 16);
}
__device__ __forceinline__ float bf2f(unsigned short h){
  unsigned u = ((unsigned)h) << 16;
  return __builtin_bit_cast(float, u);
}
__device__ __forceinline__ float sigf(float x){ return 1.0f/(1.0f + __expf(-x)); }
__device__ __forceinline__ float tanh_fast(float x){ return 2.0f/(1.0f + __expf(-2.0f*x)) - 1.0f; }

__device__ __forceinline__ void gload16(const void* g, void* l){
  __builtin_amdgcn_global_load_lds((const __attribute__((address_space(1))) void*)g,
                                   (__attribute__((address_space(3))) void*)l, 16, 0, 0);
}

// ---------------- Pass 0a: cast w_ih (2048x512 f32) -> bf16, same layout ----
__global__ __launch_bounds__(256) void k_cast_w(const float* __restrict__ w,
                                                unsigned short* __restrict__ wws){
  int idx = blockIdx.x*256 + threadIdx.x;      // float4 units; 2048*512/4 = 262144
  float4 v = ((const float4*)w)[idx];
  uint2 p;
  p.x = (unsigned)f2bf(v.x) | ((unsigned)f2bf(v.y) << 16);
  p.y = (unsigned)f2bf(v.z) | ((unsigned)f2bf(v.w) << 16);
  ((uint2*)wws)[idx] = p;
}

// ---------------- Pass 0b: x (b,s,c) f32 -> xws[b][c][s] bf16 (transpose) ---
__global__ __launch_bounds__(256) void k_cast_tx(const float* __restrict__ x,
                                                 unsigned short* __restrict__ xws){
  __shared__ float lds[64][65];
  const int tid = threadIdx.x;
  const int st = blockIdx.x, ctt = blockIdx.y, b = blockIdx.z;
  const int s0 = st*64, c0 = ctt*64;
  const int row = tid >> 2, q = tid & 3;

  const float* src = x + ((size_t)(b*S_ + s0 + row))*C_ + c0 + q*16;
  #pragma unroll
  for (int j = 0; j < 4; j++){
    float4 v = ((const float4*)src)[j];
    lds[row][q*16 + j*4 + 0] = v.x;
    lds[row][q*16 + j*4 + 1] = v.y;
    lds[row][q*16 + j*4 + 2] = v.z;
    lds[row][q*16 + j*4 + 3] = v.w;
  }
  __syncthreads();
  const int crow = row;
  #pragma unroll
  for (int j = 0; j < 2; j++){
    short8 o;
    #pragma unroll
    for (int e = 0; e < 8; e++)
      o[e] = (short)f2bf(lds[q*16 + j*8 + e][crow]);
    *(short8*)(xws + ((size_t)(b*C_ + c0 + crow))*S_ + s0 + q*16 + j*8) = o;
  }
}

// ---------------- Pass 1: MFMA GEMM + LSTM-cell epilogue --------------------
// gatesT[g, c] = sum_s wws[g,s] * xws[b,c,s]; only gate blocks {i=0, g=2, o=3}.
// Block: (kt, ct, b): 64 k-rows x 3 gates (M), 64 c (N), K = 512 in steps of 64.
// 2-phase pipeline: stage tile t+1 (double-buffered LDS) BEFORE computing
// tile t; single __syncthreads per K-step.
__global__ __launch_bounds__(256) void k_gemm(const unsigned short* __restrict__ wws,
                                              const unsigned short* __restrict__ xws,
                                              const float* __restrict__ b_ih,
                                              const float* __restrict__ b_hh,
                                              unsigned short* __restrict__ hws){
  // per-parity layout: A at [0, 24576) = [gate][row 64][swizzled 128B], B at [24576, 32768)
  __shared__ alignas(16) char lds[2][32768];

  const int tid  = threadIdx.x;
  const int w    = tid >> 6;
  const int lane = tid & 63;
  const int kt = blockIdx.x, ct = blockIdx.y, b = blockIdx.z;
  const int k0 = kt*64, c0 = ct*64;

  f32x4 acc[3][4];
  #pragma unroll
  for (int gi = 0; gi < 3; gi++)
    #pragma unroll
    for (int nf = 0; nf < 4; nf++)
      acc[gi][nf] = (f32x4){0.f, 0.f, 0.f, 0.f};

  // staging geometry: each global_load_lds = 1024B = 8 rows of 128B.
  // LDS slot (row, colb) holds global element (row, colb ^ ((row&7)<<4)).
  const int cr   = lane >> 3;                    // row within an 8-row chunk
  const int slot = ((lane & 7) ^ cr) << 4;       // pre-swizzled source col byte

  // hoisted per-chunk source/dest pointers (fully unrolled -> registers)
  const char* srcp[8];
  char*       dstp[8];
  #pragma unroll
  for (int i = 0; i < 8; i++){
    int q = w*8 + i;                             // 32 chunks: 24 A + 8 B
    if (q < 24){
      int gi = q >> 3, q8 = q & 7;
      int gr = (gi == 0 ? 0 : (gi == 1 ? 1024 : 1536));   // gate row-block base
      int grow = gr + k0 + q8*8 + cr;
      srcp[i] = (const char*)wws + ((size_t)grow*S_)*2 + slot;
      dstp[i] = &lds[0][0] + gi*8192 + q8*1024;
    } else {
      int q8 = q - 24;
      int xrow = b*C_ + c0 + q8*8 + cr;
      srcp[i] = (const char*)xws + ((size_t)xrow*S_)*2 + slot;
      dstp[i] = &lds[0][0] + 24576 + q8*1024;
    }
  }

  // prologue: stage tile 0 into parity 0
  #pragma unroll
  for (int i = 0; i < 8; i++){ gload16(srcp[i], dstp[i]); srcp[i] += 128; }
  __syncthreads();

  const int arow = w*16 + (lane & 15);
  const int lo16 = (lane >> 4) << 4;
  const int swz  = (lane & 7) << 4;

  for (int t = 0; t < 8; t++){
    const int p = t & 1;
    if (t < 7){                                  // prefetch tile t+1 into parity p^1
      #pragma unroll
      for (int i = 0; i < 8; i++){
        gload16(srcp[i], dstp[i] + (p^1)*32768);
        srcp[i] += 128;
      }
    }
    const char* base = &lds[p][0];
    #pragma unroll
    for (int ks = 0; ks < 2; ks++){
      const int colb = (ks*64 + lo16) ^ swz;
      short8 aF[3], bF[4];
      #pragma unroll
      for (int gi = 0; gi < 3; gi++)
        aF[gi] = *(const short8*)(base + gi*8192 + arow*128 + colb);
      #pragma unroll
      for (int nf = 0; nf < 4; nf++){
        int brow = nf*16 + (lane & 15);
        bF[nf] = *(const short8*)(base + 24576 + brow*128 + colb);
      }
      #pragma unroll
      for (int gi = 0; gi < 3; gi++)
        #pragma unroll
        for (int nf = 0; nf < 4; nf++)
          acc[gi][nf] = __builtin_amdgcn_mfma_f32_16x16x32_bf16(aF[gi], bF[nf], acc[gi][nf], 0, 0, 0);
    }
    __syncthreads();   // drains vmcnt (stage t+1 done) + lgkmcnt (reads of p done)
  }

  // epilogue: gates -> h, write bf16 h_ws[n][k], n = c*32 + b
  const int lkb = k0 + w*16 + ((lane >> 4) << 2);   // global k for acc regs r=0..3
  float bi[4], bg[4], bo[4];
  #pragma unroll
  for (int r = 0; r < 4; r++){
    bi[r] = b_ih[lkb + r]        + b_hh[lkb + r];          // i-gate rows [0,512)
    bg[r] = b_ih[1024 + lkb + r] + b_hh[1024 + lkb + r];   // g-gate rows [1024,1536)
    bo[r] = b_ih[1536 + lkb + r] + b_hh[1536 + lkb + r];   // o-gate rows [1536,2048)
  }
  #pragma unroll
  for (int nf = 0; nf < 4; nf++){
    int c = c0 + nf*16 + (lane & 15);
    size_t n = (size_t)c*32 + (size_t)b;
    float h[4];
    #pragma unroll
    for (int r = 0; r < 4; r++){
      float iv = acc[0][nf][r] + bi[r];
      float gv = acc[1][nf][r] + bg[r];
      float ov = acc[2][nf][r] + bo[r];
      float cc = sigf(iv) * tanh_fast(gv);
      h[r] = sigf(ov) * tanh_fast(cc);
    }
    uint2 p2;
    p2.x = (unsigned)f2bf(h[0]) | ((unsigned)f2bf(h[1]) << 16);
    p2.y = (unsigned)f2bf(h[2]) | ((unsigned)f2bf(h[3]) << 16);
    *(uint2*)(hws + n*H_ + lkb) = p2;
  }
}

// ---------------- Pass 2: out[b2,k,c2] = h_ws[b2*320+c2][k] (f32 out) -------
__global__ __launch_bounds__(256) void k_out(const unsigned short* __restrict__ hws,
                                             float* __restrict__ out){
  __shared__ float lds[64][65];
  const int tid = threadIdx.x;
  const int kt = blockIdx.x, ctt = blockIdx.y, b2 = blockIdx.z;
  const int k0 = kt*64, n0 = b2*320 + ctt*64;
  const int rr = tid >> 2, q = tid & 3;

  #pragma unroll
  for (int j = 0; j < 2; j++){
    short8 v = *(const short8*)(hws + ((size_t)(n0 + rr))*H_ + k0 + q*16 + j*8);
    #pragma unroll
    for (int e = 0; e < 8; e++)
      lds[rr][q*16 + j*8 + e] = bf2f((unsigned short)v[e]);
  }
  __syncthreads();
  const int krow = rr;
  #pragma unroll
  for (int j = 0; j < 4; j++){
    int c2l = q*16 + j*4;
    float4 o;
    o.x = lds[c2l + 0][krow];
    o.y = lds[c2l + 1][krow];
    o.z = lds[c2l + 2][krow];
    o.w = lds[c2l + 3][krow];
    *(float4*)(out + (size_t)b2*(H_*C_) + (size_t)(k0 + krow)*C_ + ctt*64 + c2l) = o;
  }
}

extern "C" void kernel_launch(void* const* d_in, const int* in_sizes, int n_in,
                              void* d_out, int out_size, void* d_ws, size_t ws_size,
                              hipStream_t stream){
  const float* x    = (const float*)d_in[0];
  const float* w_ih = (const float*)d_in[1];
  // d_in[2] = w_hh is mathematically dead (h0 = 0)
  const float* b_ih = (const float*)d_in[3];
  const float* b_hh = (const float*)d_in[4];
  float* out = (float*)d_out;

  char* ws = (char*)d_ws;
  unsigned short* wws = (unsigned short*)(ws);                           // 2 MiB  (2048*512 bf16)
  unsigned short* xws = (unsigned short*)(ws + 2097152);                 // 10 MiB (32*320*512 bf16)
  unsigned short* hws = (unsigned short*)(ws + 2097152 + 10485760);      // 10 MiB (10240*512 bf16)
  // total workspace use: ~22 MiB

  k_cast_w <<<1024, 256, 0, stream>>>(w_ih, wws);
  k_cast_tx<<<dim3(8, 5, 32), 256, 0, stream>>>(x, xws);
  k_gemm   <<<dim3(8, 5, 32), 256, 0, stream>>>(wws, xws, b_ih, b_hh, hws);
  k_out    <<<dim3(8, 5, 32), 256, 0, stream>>>(hws, out);
}

// Round 4
// 52.558 us; speedup vs baseline: 1.2381x; 1.1232x over previous
//
#include <hip/hip_runtime.h>
#include <stdint.h>

// Problem constants
#define B_  32
#define S_  512
#define C_  320
#define H_  512
#define NROW (B_*C_)          // 10240 scrambled rows: n = c*32 + b

typedef __attribute__((ext_vector_type(8))) short short8;
typedef __attribute__((ext_vector_type(4))) float f32x4;

__device__ __forceinline__ unsigned short f2bf(float x){
  unsigned u = __builtin_bit_cast(unsigned, x);
  u = u + 0x7FFFu + ((u >> 16) & 1u);          // round-to-nearest-even
  return (unsigned short)(u >> 16);
}
__device__ __forceinline__ float bf2f(unsigned short h){
  unsigned u = ((unsigned)h) << 16;
  return __builtin_bit_cast(float, u);
}
__device__ __forceinline__ float sigf(float x){ return 1.0f/(1.0f + __expf(-x)); }
__device__ __forceinline__ float tanh_fast(float x){ return 2.0f/(1.0f + __expf(-2.0f*x)) - 1.0f; }

__device__ __forceinline__ void gload16(const void* g, void* l){
  __builtin_amdgcn_global_load_lds((const __attribute__((address_space(1))) void*)g,
                                   (__attribute__((address_space(3))) void*)l, 16, 0, 0);
}

// ---- Pass 0a: compact+cast w_ih rows {i:0-511, g:1024-1535, o:1536-2047}
//      -> aws[3][512][512] bf16 (f-gate dropped: c0 = 0 makes it dead) -------
__global__ __launch_bounds__(256) void k_cast_w(const float* __restrict__ w,
                                                unsigned short* __restrict__ aws){
  int flat = blockIdx.x*256 + threadIdx.x;     // float4 units; 3*512*512/4 = 196608
  int plane = flat >> 16;                       // 65536 float4 per 512x512 plane
  int rem   = flat & 65535;
  int srow  = (plane == 0 ? 0 : (plane == 1 ? 1024 : 1536));
  float4 v = ((const float4*)w)[srow*128 + rem];   // srow*512/4 + rem
  uint2 p;
  p.x = (unsigned)f2bf(v.x) | ((unsigned)f2bf(v.y) << 16);
  p.y = (unsigned)f2bf(v.z) | ((unsigned)f2bf(v.w) << 16);
  ((uint2*)aws)[flat] = p;
}

// ---- Pass 0b: x (b,s,c) f32 -> xws[b][c][s] bf16 (transpose) ---------------
__global__ __launch_bounds__(256) void k_cast_tx(const float* __restrict__ x,
                                                 unsigned short* __restrict__ xws){
  __shared__ float lds[64][65];
  const int tid = threadIdx.x;
  const int st = blockIdx.x, ctt = blockIdx.y, b = blockIdx.z;
  const int s0 = st*64, c0 = ctt*64;
  const int row = tid >> 2, q = tid & 3;

  const float* src = x + ((size_t)(b*S_ + s0 + row))*C_ + c0 + q*16;
  #pragma unroll
  for (int j = 0; j < 4; j++){
    float4 v = ((const float4*)src)[j];
    lds[row][q*16 + j*4 + 0] = v.x;
    lds[row][q*16 + j*4 + 1] = v.y;
    lds[row][q*16 + j*4 + 2] = v.z;
    lds[row][q*16 + j*4 + 3] = v.w;
  }
  __syncthreads();
  const int crow = row;
  #pragma unroll
  for (int j = 0; j < 2; j++){
    short8 o;
    #pragma unroll
    for (int e = 0; e < 8; e++)
      o[e] = (short)f2bf(lds[q*16 + j*8 + e][crow]);
    *(short8*)(xws + ((size_t)(b*C_ + c0 + crow))*S_ + s0 + q*16 + j*8) = o;
  }
}

// ---- Pass 1: MFMA GEMM + LSTM-cell epilogue --------------------------------
// One logical GEMM: M=1536 (3 gates x 512 k), N=10240, K=512.
// Block tile: BM=192 (3 gates x 64 k) x BN=320 (one full b) x BK=64.
// Grid = 8 kt x 32 b = 256 blocks = 1 per CU. 512 threads = 8 waves (2M x 4N);
// wave owns k-rows [wm*32, wm*32+32) of ALL 3 gates (in-register gate combine)
// x 80 columns. 2-phase pipeline, double-buffered 2x64KB LDS.
// hws layout [n][k] with n = c*32 + b (the reference's batch/channel scramble).
__global__ __launch_bounds__(512, 2) void k_gemm(const unsigned short* __restrict__ aws,
                                                 const unsigned short* __restrict__ xws,
                                                 const float* __restrict__ b_ih,
                                                 const float* __restrict__ b_hh,
                                                 unsigned short* __restrict__ hws){
  // per-parity layout: A at [0, 24576) = [gate][krow 64][128B swizzled],
  //                    B at [24576, 65536) = [nrow 320][128B swizzled]
  __shared__ alignas(16) char lds[2][65536];

  const int tid  = threadIdx.x;
  const int w    = tid >> 6;
  const int lane = tid & 63;
  const int wm = w >> 2, wn = w & 3;

  // XCD-bijective decode: all 8 kt-blocks of one b land on the same XCD
  const int flat = blockIdx.x;                 // 0..255
  const int xcd = flat & 7, j = flat >> 3;
  const int b  = ((j >> 3) << 3) + xcd;        // 0..31, b % 8 == xcd
  const int kt = j & 7;
  const int k0 = kt*64;

  f32x4 acc[3][2][5];
  #pragma unroll
  for (int gi = 0; gi < 3; gi++)
    #pragma unroll
    for (int mf = 0; mf < 2; mf++)
      #pragma unroll
      for (int nf = 0; nf < 5; nf++)
        acc[gi][mf][nf] = (f32x4){0.f, 0.f, 0.f, 0.f};

  // staging: each global_load_lds = 1024B = 8 rows x 128B.
  // LDS slot (row, colb) holds global element (row, colb ^ ((row&7)<<4)).
  const int cr   = lane >> 3;
  const int slot = ((lane & 7) ^ cr) << 4;

  // 64 chunks total (24 A + 40 B), 8 per wave — hoisted pointers
  const char* srcp[8];
  char*       dstp[8];
  #pragma unroll
  for (int i = 0; i < 8; i++){
    int q = w*8 + i;
    if (q < 24){
      int gi = q >> 3, q8 = q & 7;
      int grow = gi*512 + k0 + q8*8 + cr;
      srcp[i] = (const char*)aws + ((size_t)grow*S_)*2 + slot;
      dstp[i] = &lds[0][0] + gi*8192 + q8*1024;
    } else {
      int q8 = q - 24;                         // 0..39
      int xrow = b*C_ + q8*8 + cr;
      srcp[i] = (const char*)xws + ((size_t)xrow*S_)*2 + slot;
      dstp[i] = &lds[0][0] + 24576 + q8*1024;
    }
  }

  // prologue: stage tile 0 into parity 0
  #pragma unroll
  for (int i = 0; i < 8; i++){ gload16(srcp[i], dstp[i]); srcp[i] += 128; }
  __syncthreads();

  const int lo16 = (lane >> 4) << 4;
  const int swz  = (lane & 7) << 4;
  const int l15  = lane & 15;

  for (int t = 0; t < 8; t++){
    const int p = t & 1;
    if (t < 7){                                // prefetch tile t+1 into parity p^1
      #pragma unroll
      for (int i = 0; i < 8; i++){
        gload16(srcp[i], dstp[i] + ((p^1) << 16));
        srcp[i] += 128;
      }
    }
    const char* base = &lds[p][0];
    #pragma unroll
    for (int ks = 0; ks < 2; ks++){
      const int colb = (ks*64 + lo16) ^ swz;
      short8 aF[3][2], bF[5];
      #pragma unroll
      for (int gi = 0; gi < 3; gi++)
        #pragma unroll
        for (int mf = 0; mf < 2; mf++)
          aF[gi][mf] = *(const short8*)(base + gi*8192 + (wm*32 + mf*16 + l15)*128 + colb);
      #pragma unroll
      for (int nf = 0; nf < 5; nf++)
        bF[nf] = *(const short8*)(base + 24576 + (wn*80 + nf*16 + l15)*128 + colb);
      #pragma unroll
      for (int gi = 0; gi < 3; gi++)
        #pragma unroll
        for (int mf = 0; mf < 2; mf++)
          #pragma unroll
          for (int nf = 0; nf < 5; nf++)
            acc[gi][mf][nf] = __builtin_amdgcn_mfma_f32_16x16x32_bf16(aF[gi][mf], bF[nf], acc[gi][mf][nf], 0, 0, 0);
    }
    __syncthreads();   // drains vmcnt (stage t+1 done) + lgkmcnt (reads of p done)
  }

  // epilogue: gate-combine -> h, write bf16 hws[n][k], n = c*32 + b.
  // Lane groups {l15, l15+16, l15+32, l15+48} share n and fill 16 contiguous k
  // (32B) per (mf,nf) store -> wave-coalesced 32B segments.
  #pragma unroll
  for (int mf = 0; mf < 2; mf++){
    const int kb = k0 + wm*32 + mf*16 + ((lane >> 4) << 2);   // + r
    float bi[4], bg[4], bo[4];
    #pragma unroll
    for (int r = 0; r < 4; r++){
      bi[r] = b_ih[kb + r]        + b_hh[kb + r];
      bg[r] = b_ih[1024 + kb + r] + b_hh[1024 + kb + r];
      bo[r] = b_ih[1536 + kb + r] + b_hh[1536 + kb + r];
    }
    #pragma unroll
    for (int nf = 0; nf < 5; nf++){
      const int c = wn*80 + nf*16 + l15;
      const size_t n = (size_t)c*32 + (size_t)b;     // the scramble: c*B + b
      float h[4];
      #pragma unroll
      for (int r = 0; r < 4; r++){
        float iv = acc[0][mf][nf][r] + bi[r];
        float gv = acc[1][mf][nf][r] + bg[r];
        float ov = acc[2][mf][nf][r] + bo[r];
        float cc = sigf(iv) * tanh_fast(gv);
        h[r] = sigf(ov) * tanh_fast(cc);
      }
      uint2 p2;
      p2.x = (unsigned)f2bf(h[0]) | ((unsigned)f2bf(h[1]) << 16);
      p2.y = (unsigned)f2bf(h[2]) | ((unsigned)f2bf(h[3]) << 16);
      *(uint2*)(hws + n*H_ + kb) = p2;
    }
  }
}

// ---- Pass 2: out[b2,k,c2] = f32(hws[b2*320+c2][k]) — LDS transpose ---------
__global__ __launch_bounds__(256) void k_out(const unsigned short* __restrict__ hws,
                                             float* __restrict__ out){
  __shared__ float lds[64][65];
  const int tid = threadIdx.x;
  const int kt = blockIdx.x, ctt = blockIdx.y, b2 = blockIdx.z;
  const int k0 = kt*64, n0 = b2*320 + ctt*64;
  const int rr = tid >> 2, q = tid & 3;

  #pragma unroll
  for (int j = 0; j < 2; j++){
    short8 v = *(const short8*)(hws + ((size_t)(n0 + rr))*H_ + k0 + q*16 + j*8);
    #pragma unroll
    for (int e = 0; e < 8; e++)
      lds[rr][q*16 + j*8 + e] = bf2f((unsigned short)v[e]);
  }
  __syncthreads();
  const int krow = rr;
  #pragma unroll
  for (int j = 0; j < 4; j++){
    int c2l = q*16 + j*4;
    float4 o;
    o.x = lds[c2l + 0][krow];
    o.y = lds[c2l + 1][krow];
    o.z = lds[c2l + 2][krow];
    o.w = lds[c2l + 3][krow];
    *(float4*)(out + (size_t)b2*(H_*C_) + (size_t)(k0 + krow)*C_ + ctt*64 + c2l) = o;
  }
}

extern "C" void kernel_launch(void* const* d_in, const int* in_sizes, int n_in,
                              void* d_out, int out_size, void* d_ws, size_t ws_size,
                              hipStream_t stream){
  const float* x    = (const float*)d_in[0];
  const float* w_ih = (const float*)d_in[1];
  // d_in[2] = w_hh is mathematically dead (h0 = 0)
  const float* b_ih = (const float*)d_in[3];
  const float* b_hh = (const float*)d_in[4];
  float* out = (float*)d_out;

  char* ws = (char*)d_ws;
  unsigned short* aws = (unsigned short*)(ws);                           // 1.5 MiB (3*512*512 bf16)
  unsigned short* xws = (unsigned short*)(ws + 2097152);                 // 10 MiB  (10240*512 bf16)
  unsigned short* hws = (unsigned short*)(ws + 2097152 + 10485760);      // 10 MiB  (10240*512 bf16)
  // total workspace use: ~22 MiB

  k_cast_w <<<768, 256, 0, stream>>>(w_ih, aws);
  k_cast_tx<<<dim3(8, 5, 32), 256, 0, stream>>>(x, xws);
  k_gemm   <<<256, 512, 0, stream>>>(aws, xws, b_ih, b_hh, hws);
  k_out    <<<dim3(8, 5, 32), 256, 0, stream>>>(hws, out);
}